// Round 1
// baseline (36.518 us; speedup 1.0000x reference)
//
#include <hip/hip_runtime.h>
#include <math.h>

// Problem constants (from reference): B=256, C=500, D=256
#define BB 256
#define CC 500
#define DD 256
#define CPB 50      // c-rows per block
#define CHUNKS 10   // CC / CPB
#define MARGIN 0.3f

// wf layout: wf[c][b][d], flat index ((size_t)c*BB + b)*DD + d
// One wave (64 lanes) reads one (c,b) row as 64 x float4 = 256 floats, fully coalesced.

__global__ __launch_bounds__(256) void fused_loss_kernel(
    const float* __restrict__ logits,   // [B, C]
    const float* __restrict__ wf,       // [C, B, D]
    const int*   __restrict__ labels,   // [B, C]
    float*       __restrict__ out)      // [B]
{
    const int b    = blockIdx.y;
    const int c0   = blockIdx.x * CPB;
    const int tid  = threadIdx.x;
    const int wave = tid >> 6;
    const int lane = tid & 63;

    float acc = 0.0f;   // lane0-of-wave holds rejection partials; all lanes hold BCE partials

    // ---- rejection term: rows c0+wave, c0+wave+4, ... -------------------
    int ci = wave;
    const float* rowp = wf + ((size_t)(c0 + ci) * BB + b) * DD + lane * 4;
    float4 v = *reinterpret_cast<const float4*>(rowp);
    for (; ci < CPB; ci += 4) {
        float4 cur = v;
        const int cn = ci + 4;
        if (cn < CPB) {
            // prefetch next row while we do the shuffle-reduce chain
            v = *reinterpret_cast<const float4*>(
                    wf + ((size_t)(c0 + cn) * BB + b) * DD + lane * 4);
        }
        float m = fmaxf(fmaxf(cur.x, cur.y), fmaxf(cur.z, cur.w));
        #pragma unroll
        for (int off = 32; off > 0; off >>= 1)
            m = fmaxf(m, __shfl_xor(m, off));
        if (lane == 0) {
            if (labels[b * CC + (c0 + ci)] == 0) {
                const float s = 1.0f / (1.0f + __expf(-m));   // sigmoid(row max)
                acc += fmaxf(s - MARGIN, 0.0f);
            }
        }
    }

    // ---- BCE term (only chunk-0 block for this b) -----------------------
    if (blockIdx.x == 0) {
        for (int c = tid; c < CC; c += 256) {
            const float x = logits[b * CC + c];
            const float y = (float)labels[b * CC + c];
            // stable: -(y*logsig(x) + (1-y)*logsig(-x)) = max(x,0) - x*y + log1p(exp(-|x|))
            acc += fmaxf(x, 0.0f) - x * y + log1pf(__expf(-fabsf(x)));
        }
    }

    // ---- block reduce + atomic accumulate -------------------------------
    #pragma unroll
    for (int off = 32; off > 0; off >>= 1)
        acc += __shfl_down(acc, off);

    __shared__ float sm[4];
    if (lane == 0) sm[wave] = acc;
    __syncthreads();
    if (tid == 0)
        atomicAdd(&out[b], sm[0] + sm[1] + sm[2] + sm[3]);
}

extern "C" void kernel_launch(void* const* d_in, const int* in_sizes, int n_in,
                              void* d_out, int out_size, void* d_ws, size_t ws_size,
                              hipStream_t stream) {
    const float* logits = (const float*)d_in[0];
    const float* wf     = (const float*)d_in[1];
    const int*   labels = (const int*)d_in[2];
    float*       out    = (float*)d_out;

    hipMemsetAsync(out, 0, out_size * sizeof(float), stream);

    dim3 grid(CHUNKS, BB);
    dim3 block(256);
    fused_loss_kernel<<<grid, block, 0, stream>>>(logits, wf, labels, out);
}